// Round 7
// baseline (1410.699 us; speedup 1.0000x reference)
//
#include <hip/hip_runtime.h>
#include <cstdint>
#include <cstddef>

#define BB 256
#define TT 250
#define DIN 700
#define H1 256
#define H2 256
#define DOUT 20
#define BJ0 0.01f
#define BETAC 1.8f
#define DUMMY 256                 // zero row index in every padded table

typedef float f32x4 __attribute__((ext_vector_type(4)));

// Workspace layout (floats). Each weight table has one extra ZERO row.
//   wT1  [701*256] @ 0
//   wT11 [257*256] @ 179456
//   wT12 [257*256] @ 245248
//   wT22 [257*256] @ 311040
//   wT2o [257*20 ] @ 376832
//   Xp   [250*256*256] @ 381972
#define OFF_WT11 179456
#define OFF_WT12 245248
#define OFF_WT22 311040
#define OFF_WT2O 376832
#define OFF_XP   381972
#define N_TRANS  381972

__global__ void transpose_all_k(const float* __restrict__ w_i2h1,
                                const float* __restrict__ w_h12h1,
                                const float* __restrict__ w_h12h2,
                                const float* __restrict__ w_h22h2,
                                const float* __restrict__ w_h2o,
                                float* __restrict__ ws) {
    int i = blockIdx.x * blockDim.x + threadIdx.x;
    if (i < 179456) { int d = i >> 8, h = i & 255;
        ws[i] = (d < DIN) ? w_i2h1[h * DIN + d] : 0.f; return; }
    i -= 179456;
    if (i < 65792) { int d = i >> 8, h = i & 255;
        ws[OFF_WT11 + i] = (d < H1) ? w_h12h1[h * H1 + d] : 0.f; return; }
    i -= 65792;
    if (i < 65792) { int d = i >> 8, h = i & 255;
        ws[OFF_WT12 + i] = (d < H1) ? w_h12h2[h * H1 + d] : 0.f; return; }
    i -= 65792;
    if (i < 65792) { int d = i >> 8, h = i & 255;
        ws[OFF_WT22 + i] = (d < H2) ? w_h22h2[h * H2 + d] : 0.f; return; }
    i -= 65792;
    if (i < 5140)  { int j = i / 20, h = i % 20;
        ws[OFF_WT2O + i] = (j < H2) ? w_h2o[h * H2 + j] : 0.f; return; }
}

// ---------------------------------------------------------------------------
// Xp[t][b][h] = b_h1[h] + sum_{d active} wT1[d*256 + h]   (unchanged, works)
// ---------------------------------------------------------------------------
__global__ __launch_bounds__(256) void xproj_k(const float* __restrict__ x,
                                               const float* __restrict__ wT1,
                                               const float* __restrict__ b_h1,
                                               float* __restrict__ Xp) {
    const int lane = threadIdx.x & 63;
    const int wv   = threadIdx.x >> 6;
    const int bt   = blockIdx.x * 4 + wv;   // grid = T*B/4 = 16000
    const int b    = bt & (BB - 1);
    const int t    = bt >> 8;

    __shared__ __align__(16) int lst[4][712];

    const float* xrow = x + ((size_t)b * TT + t) * DIN;
    int cnt = 0;
    for (int c = 0; c < 11; ++c) {
        int d = c * 64 + lane;
        bool p = false;
        if (d < DIN) p = (__builtin_nontemporal_load(xrow + d) != 0.0f);
        unsigned long long m = __ballot(p ? 1 : 0);
        if (p) {
            int pos = cnt + __popcll(m & ((1ull << lane) - 1ull));
            lst[wv][pos] = d;
        }
        cnt += __popcll(m);
    }
    int cntp = (cnt + 7) & ~7;
    if (lane < cntp - cnt) lst[wv][cnt + lane] = DIN;   // zero row pad
    __syncthreads();

    f32x4 acc0 = *(const f32x4*)(b_h1 + lane * 4);
    f32x4 acc1 = {0.f, 0.f, 0.f, 0.f};
    const int lo = lane * 4;
    for (int k = 0; k < cntp; k += 8) {
        int4 ja = *(const int4*)&lst[wv][k];
        int4 jb = *(const int4*)&lst[wv][k + 4];
        f32x4 w0 = *(const f32x4*)(wT1 + ((size_t)ja.x << 8) + lo);
        f32x4 w1 = *(const f32x4*)(wT1 + ((size_t)ja.y << 8) + lo);
        f32x4 w2 = *(const f32x4*)(wT1 + ((size_t)ja.z << 8) + lo);
        f32x4 w3 = *(const f32x4*)(wT1 + ((size_t)ja.w << 8) + lo);
        f32x4 w4 = *(const f32x4*)(wT1 + ((size_t)jb.x << 8) + lo);
        f32x4 w5 = *(const f32x4*)(wT1 + ((size_t)jb.y << 8) + lo);
        f32x4 w6 = *(const f32x4*)(wT1 + ((size_t)jb.z << 8) + lo);
        f32x4 w7 = *(const f32x4*)(wT1 + ((size_t)jb.w << 8) + lo);
        acc0 += (w0 + w1) + (w2 + w3);
        acc1 += (w4 + w5) + (w6 + w7);
    }
    acc0 += acc1;
    __builtin_nontemporal_store(acc0, (f32x4*)(Xp + ((size_t)t * BB + b) * H1 + lo));
}

// ---------------------------------------------------------------------------
// rec_k: one 256-thread block per batch element.
// Update phases: thread h = neuron h (as before).
// Gather phases: wave wv handles row-subset {pos ≡ wv mod 4} of each spike
// list; lane covers columns 4*lane..4*lane+3 via float4 -> per-thread load
// count drops 4x vs column-per-thread. Cross-wave combine via LDS psums.
// Sub-lists are deinterleaved (L[q][slot], q=pos&3, slot=pos>>2) and padded
// (flat count to multiple of 64, zero-row dummies) so loops are branch-free.
// ---------------------------------------------------------------------------
__global__ __launch_bounds__(256, 1) void rec_k(
    const float* __restrict__ Xp,
    const float* __restrict__ wT11, const float* __restrict__ wT12,
    const float* __restrict__ wT22, const float* __restrict__ wT2o,
    const float* __restrict__ b_h2, const float* __restrict__ b_o,
    const float* __restrict__ tau_adp_h1, const float* __restrict__ tau_adp_h2,
    const float* __restrict__ tau_m_h1, const float* __restrict__ tau_m_h2,
    const float* __restrict__ tau_m_o,
    float* __restrict__ out) {
    const int h    = threadIdx.x;
    const int lane = h & 63;
    const int wv   = h >> 6;
    const int b    = blockIdx.x;
    const int col4 = lane * 4;

    __shared__ __align__(16) int L1[4][64];
    __shared__ __align__(16) int L2[4][64];
    __shared__ unsigned long long wmask[4];
    __shared__ float psumA[4][256];   // wT11 partials
    __shared__ float psumB[4][256];   // wT22 partials
    __shared__ float psumD[4][256];   // wT12 partials
    __shared__ float psumO[4][DOUT];  // wT2o partials
    __shared__ float smo[DOUT];

    const float alpha1 = expf(-1.0f / tau_m_h1[h]);
    const float ro1    = expf(-1.0f / tau_adp_h1[h]);
    const float alpha2 = expf(-1.0f / tau_m_h2[h]);
    const float ro2    = expf(-1.0f / tau_adp_h2[h]);
    const float bh2v   = b_h2[h];
    float alpo = 0.f, bov = 0.f;
    if (h < DOUT) { alpo = expf(-1.0f / tau_m_o[h]); bov = b_o[h]; }

    float mem1 = 0.f, spk1 = 0.f, bb1v = BJ0;
    float mem2 = 0.f, spk2 = 0.f, bb2v = BJ0;
    float memo = 0.f, accs = 0.f;
    int LPC = 0;     // common padded sub-list length for P1
    int LP1 = 0;     // fresh lst1 sub-list length for P3

    float xp_cur = Xp[(size_t)b * H1 + h];   // t=0

    for (int t = 0; t < TT; ++t) {
        float xp_nxt = 0.f;
        if (t + 1 < TT)
            xp_nxt = Xp[((size_t)(t + 1) * BB + b) * H1 + h];

        // ---- P1: wave-parallel fused gather (wT11 | wT22 | wT2o) ----
        f32x4 accA = {0.f, 0.f, 0.f, 0.f};
        f32x4 accB = {0.f, 0.f, 0.f, 0.f};
        float accO = 0.f;
        const bool doOut = (t > 0) && (lane < DOUT);
        {
            const int* l1 = L1[wv];
            const int* l2 = L2[wv];
            for (int k = 0; k < LPC; k += 16) {
                int4 p0 = *(const int4*)(l1 + k);
                int4 p1 = *(const int4*)(l1 + k + 4);
                int4 p2 = *(const int4*)(l1 + k + 8);
                int4 p3 = *(const int4*)(l1 + k + 12);
                int4 q0 = *(const int4*)(l2 + k);
                int4 q1 = *(const int4*)(l2 + k + 4);
                int4 q2 = *(const int4*)(l2 + k + 8);
                int4 q3 = *(const int4*)(l2 + k + 12);
                f32x4 a0  = *(const f32x4*)(wT11 + (p0.x << 8) + col4);
                f32x4 a1  = *(const f32x4*)(wT11 + (p0.y << 8) + col4);
                f32x4 a2  = *(const f32x4*)(wT11 + (p0.z << 8) + col4);
                f32x4 a3  = *(const f32x4*)(wT11 + (p0.w << 8) + col4);
                f32x4 a4  = *(const f32x4*)(wT11 + (p1.x << 8) + col4);
                f32x4 a5  = *(const f32x4*)(wT11 + (p1.y << 8) + col4);
                f32x4 a6  = *(const f32x4*)(wT11 + (p1.z << 8) + col4);
                f32x4 a7  = *(const f32x4*)(wT11 + (p1.w << 8) + col4);
                f32x4 a8  = *(const f32x4*)(wT11 + (p2.x << 8) + col4);
                f32x4 a9  = *(const f32x4*)(wT11 + (p2.y << 8) + col4);
                f32x4 a10 = *(const f32x4*)(wT11 + (p2.z << 8) + col4);
                f32x4 a11 = *(const f32x4*)(wT11 + (p2.w << 8) + col4);
                f32x4 a12 = *(const f32x4*)(wT11 + (p3.x << 8) + col4);
                f32x4 a13 = *(const f32x4*)(wT11 + (p3.y << 8) + col4);
                f32x4 a14 = *(const f32x4*)(wT11 + (p3.z << 8) + col4);
                f32x4 a15 = *(const f32x4*)(wT11 + (p3.w << 8) + col4);
                f32x4 b0  = *(const f32x4*)(wT22 + (q0.x << 8) + col4);
                f32x4 b1  = *(const f32x4*)(wT22 + (q0.y << 8) + col4);
                f32x4 b2  = *(const f32x4*)(wT22 + (q0.z << 8) + col4);
                f32x4 b3  = *(const f32x4*)(wT22 + (q0.w << 8) + col4);
                f32x4 b4  = *(const f32x4*)(wT22 + (q1.x << 8) + col4);
                f32x4 b5  = *(const f32x4*)(wT22 + (q1.y << 8) + col4);
                f32x4 b6  = *(const f32x4*)(wT22 + (q1.z << 8) + col4);
                f32x4 b7  = *(const f32x4*)(wT22 + (q1.w << 8) + col4);
                f32x4 b8  = *(const f32x4*)(wT22 + (q2.x << 8) + col4);
                f32x4 b9  = *(const f32x4*)(wT22 + (q2.y << 8) + col4);
                f32x4 b10 = *(const f32x4*)(wT22 + (q2.z << 8) + col4);
                f32x4 b11 = *(const f32x4*)(wT22 + (q2.w << 8) + col4);
                f32x4 b12 = *(const f32x4*)(wT22 + (q3.x << 8) + col4);
                f32x4 b13 = *(const f32x4*)(wT22 + (q3.y << 8) + col4);
                f32x4 b14 = *(const f32x4*)(wT22 + (q3.z << 8) + col4);
                f32x4 b15 = *(const f32x4*)(wT22 + (q3.w << 8) + col4);
                float o0 = 0.f, o1 = 0.f, o2 = 0.f, o3 = 0.f;
                if (doOut) {
                    o0 = wT2o[q0.x * DOUT + lane] + wT2o[q0.y * DOUT + lane]
                       + wT2o[q0.z * DOUT + lane] + wT2o[q0.w * DOUT + lane];
                    o1 = wT2o[q1.x * DOUT + lane] + wT2o[q1.y * DOUT + lane]
                       + wT2o[q1.z * DOUT + lane] + wT2o[q1.w * DOUT + lane];
                    o2 = wT2o[q2.x * DOUT + lane] + wT2o[q2.y * DOUT + lane]
                       + wT2o[q2.z * DOUT + lane] + wT2o[q2.w * DOUT + lane];
                    o3 = wT2o[q3.x * DOUT + lane] + wT2o[q3.y * DOUT + lane]
                       + wT2o[q3.z * DOUT + lane] + wT2o[q3.w * DOUT + lane];
                }
                accA += (((a0 + a1) + (a2 + a3)) + ((a4 + a5) + (a6 + a7)))
                      + (((a8 + a9) + (a10 + a11)) + ((a12 + a13) + (a14 + a15)));
                accB += (((b0 + b1) + (b2 + b3)) + ((b4 + b5) + (b6 + b7)))
                      + (((b8 + b9) + (b10 + b11)) + ((b12 + b13) + (b14 + b15)));
                accO += (o0 + o1) + (o2 + o3);
            }
        }
        *(f32x4*)&psumA[wv][col4] = accA;
        *(f32x4*)&psumB[wv][col4] = accB;
        if (lane < DOUT) psumO[wv][lane] = accO;
        __syncthreads();                               // B1

        // ---- U1: layer-1 update; output memo for step t-1 ----
        float r1 = (psumA[0][h] + psumA[1][h]) + (psumA[2][h] + psumA[3][h]);
        bb1v = ro1 * bb1v + BETAC * (1.f - ro1) * spk1;
        mem1 = mem1 * alpha1 - bb1v * spk1 + (1.f - alpha1) * (xp_cur + r1);
        float ns1 = (mem1 - bb1v - BJ0) > 0.f ? 1.f : 0.f;
        spk1 = ns1;
        unsigned long long m1 = __ballot(ns1 != 0.f ? 1 : 0);
        if (lane == 0) wmask[wv] = m1;
        const bool doo = (h < DOUT) && (t > 0);
        if (doo) {
            float rO = (psumO[0][h] + psumO[1][h]) + (psumO[2][h] + psumO[3][h]);
            memo = memo * alpo + (1.f - alpo) * (bov + rO);
            smo[h] = memo;
        }
        __syncthreads();                               // B2

        // ---- P2b: build deinterleaved lst1 (pad flat to 64-mult) ----
        {
            int pos = __popcll(m1 & ((1ull << lane) - 1ull));
            int tot = 0;
            for (int w = 0; w < 4; ++w) {
                unsigned long long mw = wmask[w];
                if (w < wv) pos += __popcll(mw);
                tot += __popcll(mw);
            }
            if (ns1 != 0.f) L1[pos & 3][pos >> 2] = h;
            int np = (tot + 63) & ~63;
            if (h < np - tot) { int p = tot + h; L1[p & 3][p >> 2] = DUMMY; }
            LP1 = np >> 2;
        }
        if (doo) {
            float mx = smo[0];
            for (int i = 1; i < DOUT; ++i) mx = fmaxf(mx, smo[i]);
            float s = 0.f;
            for (int i = 0; i < DOUT; ++i) s += expf(smo[i] - mx);
            accs += expf(memo - mx) / s;
        }
        __syncthreads();                               // B3

        // ---- P3: wave-parallel gather wT12 over fresh lst1 ----
        f32x4 accD = {0.f, 0.f, 0.f, 0.f};
        {
            const int* l1 = L1[wv];
            for (int k = 0; k < LP1; k += 16) {
                int4 p0 = *(const int4*)(l1 + k);
                int4 p1 = *(const int4*)(l1 + k + 4);
                int4 p2 = *(const int4*)(l1 + k + 8);
                int4 p3 = *(const int4*)(l1 + k + 12);
                f32x4 d0  = *(const f32x4*)(wT12 + (p0.x << 8) + col4);
                f32x4 d1  = *(const f32x4*)(wT12 + (p0.y << 8) + col4);
                f32x4 d2  = *(const f32x4*)(wT12 + (p0.z << 8) + col4);
                f32x4 d3  = *(const f32x4*)(wT12 + (p0.w << 8) + col4);
                f32x4 d4  = *(const f32x4*)(wT12 + (p1.x << 8) + col4);
                f32x4 d5  = *(const f32x4*)(wT12 + (p1.y << 8) + col4);
                f32x4 d6  = *(const f32x4*)(wT12 + (p1.z << 8) + col4);
                f32x4 d7  = *(const f32x4*)(wT12 + (p1.w << 8) + col4);
                f32x4 d8  = *(const f32x4*)(wT12 + (p2.x << 8) + col4);
                f32x4 d9  = *(const f32x4*)(wT12 + (p2.y << 8) + col4);
                f32x4 d10 = *(const f32x4*)(wT12 + (p2.z << 8) + col4);
                f32x4 d11 = *(const f32x4*)(wT12 + (p2.w << 8) + col4);
                f32x4 d12 = *(const f32x4*)(wT12 + (p3.x << 8) + col4);
                f32x4 d13 = *(const f32x4*)(wT12 + (p3.y << 8) + col4);
                f32x4 d14 = *(const f32x4*)(wT12 + (p3.z << 8) + col4);
                f32x4 d15 = *(const f32x4*)(wT12 + (p3.w << 8) + col4);
                accD += (((d0 + d1) + (d2 + d3)) + ((d4 + d5) + (d6 + d7)))
                      + (((d8 + d9) + (d10 + d11)) + ((d12 + d13) + (d14 + d15)));
            }
        }
        *(f32x4*)&psumD[wv][col4] = accD;
        __syncthreads();                               // B4

        // ---- U2: layer-2 update ----
        float r2 = (psumB[0][h] + psumB[1][h]) + (psumB[2][h] + psumB[3][h]);
        float r3 = (psumD[0][h] + psumD[1][h]) + (psumD[2][h] + psumD[3][h]);
        bb2v = ro2 * bb2v + BETAC * (1.f - ro2) * spk2;
        mem2 = mem2 * alpha2 - bb2v * spk2 + (1.f - alpha2) * (bh2v + r2 + r3);
        float ns2 = (mem2 - bb2v - BJ0) > 0.f ? 1.f : 0.f;
        spk2 = ns2;
        unsigned long long m2 = __ballot(ns2 != 0.f ? 1 : 0);
        if (lane == 0) wmask[wv] = m2;
        __syncthreads();                               // B5

        // ---- P4b: build lst2; pad BOTH flat lists to common length ----
        {
            int pos = __popcll(m2 & ((1ull << lane) - 1ull));
            int tot = 0;
            for (int w = 0; w < 4; ++w) {
                unsigned long long mw = wmask[w];
                if (w < wv) pos += __popcll(mw);
                tot += __popcll(mw);
            }
            if (ns2 != 0.f) L2[pos & 3][pos >> 2] = h;
            int n2P = (tot + 63) & ~63;
            int n1P = LP1 << 2;
            int nC  = n1P > n2P ? n1P : n2P;
            if (h < nC - tot) { int p = tot + h; L2[p & 3][p >> 2] = DUMMY; }
            if (h < nC - n1P) { int p = n1P + h; L1[p & 3][p >> 2] = DUMMY; }
            LPC = nC >> 2;
        }
        __syncthreads();                               // B6

        xp_cur = xp_nxt;
    }

    // ---- Epilogue: output + softmax for final timestep ----
    {
        float accO = 0.f;
        const int* l2 = L2[wv];
        if (lane < DOUT)
            for (int k = 0; k < LPC; ++k) accO += wT2o[l2[k] * DOUT + lane];
        if (lane < DOUT) psumO[wv][lane] = accO;
    }
    __syncthreads();
    if (h < DOUT) {
        float rO = (psumO[0][h] + psumO[1][h]) + (psumO[2][h] + psumO[3][h]);
        memo = memo * alpo + (1.f - alpo) * (bov + rO);
        smo[h] = memo;
    }
    __syncthreads();
    if (h < DOUT) {
        float mx = smo[0];
        for (int i = 1; i < DOUT; ++i) mx = fmaxf(mx, smo[i]);
        float s = 0.f;
        for (int i = 0; i < DOUT; ++i) s += expf(smo[i] - mx);
        accs += expf(memo - mx) / s;
        out[b * DOUT + h] = accs;
    }
}

extern "C" void kernel_launch(void* const* d_in, const int* in_sizes, int n_in,
                              void* d_out, int out_size, void* d_ws, size_t ws_size,
                              hipStream_t stream) {
    const float* x          = (const float*)d_in[0];
    const float* w_i2h1     = (const float*)d_in[1];
    const float* w_h12h1    = (const float*)d_in[2];
    const float* w_h12h2    = (const float*)d_in[3];
    const float* w_h22h2    = (const float*)d_in[4];
    const float* w_h2o      = (const float*)d_in[5];
    const float* b_h1       = (const float*)d_in[6];
    const float* b_h2       = (const float*)d_in[7];
    const float* b_o        = (const float*)d_in[8];
    const float* tau_adp_h1 = (const float*)d_in[9];
    const float* tau_adp_h2 = (const float*)d_in[10];
    const float* tau_m_h1   = (const float*)d_in[11];
    const float* tau_m_h2   = (const float*)d_in[12];
    const float* tau_m_o    = (const float*)d_in[13];

    float* ws   = (float*)d_ws;
    float* wT1  = ws;
    float* wT11 = ws + OFF_WT11;
    float* wT12 = ws + OFF_WT12;
    float* wT22 = ws + OFF_WT22;
    float* wT2o = ws + OFF_WT2O;
    float* Xp   = ws + OFF_XP;

    transpose_all_k<<<(N_TRANS + 255) / 256, 256, 0, stream>>>(
        w_i2h1, w_h12h1, w_h12h2, w_h22h2, w_h2o, ws);

    xproj_k<<<(TT * BB) / 4, 256, 0, stream>>>(x, wT1, b_h1, Xp);

    rec_k<<<BB, 256, 0, stream>>>(Xp, wT11, wT12, wT22, wT2o,
                                  b_h2, b_o, tau_adp_h1, tau_adp_h2,
                                  tau_m_h1, tau_m_h2, tau_m_o,
                                  (float*)d_out);
}

// Round 8
// 1110.076 us; speedup vs baseline: 1.2708x; 1.2708x over previous
//
#include <hip/hip_runtime.h>
#include <cstdint>
#include <cstddef>

#define BB 256
#define TT 250
#define DIN 700
#define H1 256
#define H2 256
#define DOUT 20
#define BJ0 0.01f
#define BETAC 1.8f
#define DUMMY 256                 // zero row index in every padded table
#define IQSCALE 3.814697265625e-06f   // 2^-18

typedef float f32x4 __attribute__((ext_vector_type(4)));
typedef short s16x4 __attribute__((ext_vector_type(4)));

// ---------------------------------------------------------------------------
// Workspace layout. int16 tables (element offsets in shorts from ws base):
//   sT1  [701*256] @ 0        (row 700 = zeros)
//   sT11 [257*256] @ 179456   (row 256 = zeros)
//   sT12 [257*256] @ 245248
//   sT22 [257*256] @ 311040   (end: 376832 shorts = 753664 bytes)
// fp32 region (float offsets from ws base):
//   wT2o [257*20]  @ f188416  (row 256 = zeros)
//   Xp   [250*256*256] @ f193556  (byte 774224, 16B aligned)
// ---------------------------------------------------------------------------
#define SOFF_T11 179456
#define SOFF_T12 245248
#define SOFF_T22 311040
#define FOFF_W2O 188416
#define FOFF_XP  193556
#define N_TRANS  381972

__device__ __forceinline__ short q18(float w) {
    float s = w * 262144.0f;
    s = fminf(fmaxf(s, -32767.0f), 32767.0f);
    return (short)__float2int_rn(s);
}

__global__ void transpose_all_k(const float* __restrict__ w_i2h1,
                                const float* __restrict__ w_h12h1,
                                const float* __restrict__ w_h12h2,
                                const float* __restrict__ w_h22h2,
                                const float* __restrict__ w_h2o,
                                short* __restrict__ sws,
                                float* __restrict__ fws) {
    int i = blockIdx.x * blockDim.x + threadIdx.x;
    if (i < 179456) { int d = i >> 8, h = i & 255;
        sws[i] = q18((d < DIN) ? w_i2h1[h * DIN + d] : 0.f); return; }
    i -= 179456;
    if (i < 65792) { int d = i >> 8, h = i & 255;
        sws[SOFF_T11 + i] = q18((d < H1) ? w_h12h1[h * H1 + d] : 0.f); return; }
    i -= 65792;
    if (i < 65792) { int d = i >> 8, h = i & 255;
        sws[SOFF_T12 + i] = q18((d < H1) ? w_h12h2[h * H1 + d] : 0.f); return; }
    i -= 65792;
    if (i < 65792) { int d = i >> 8, h = i & 255;
        sws[SOFF_T22 + i] = q18((d < H2) ? w_h22h2[h * H2 + d] : 0.f); return; }
    i -= 65792;
    if (i < 5140)  { int j = i / 20, h = i % 20;
        fws[FOFF_W2O + i] = (j < H2) ? w_h2o[h * H2 + j] : 0.f; return; }
}

// ---------------------------------------------------------------------------
// Xp[t][b][h] = b_h1[h] + (Σ_{d active} sT1[d*256+h]) * 2^-18
// One wave per (b,t); lane covers 4 cols via short4 (8B) loads; int32 accum.
// ---------------------------------------------------------------------------
__global__ __launch_bounds__(256) void xproj_k(const float* __restrict__ x,
                                               const short* __restrict__ sT1,
                                               const float* __restrict__ b_h1,
                                               float* __restrict__ Xp) {
    const int lane = threadIdx.x & 63;
    const int wv   = threadIdx.x >> 6;
    const int bt   = blockIdx.x * 4 + wv;   // grid = T*B/4 = 16000
    const int b    = bt & (BB - 1);
    const int t    = bt >> 8;

    __shared__ __align__(16) int lst[4][712];

    const float* xrow = x + ((size_t)b * TT + t) * DIN;
    int cnt = 0;
    for (int c = 0; c < 11; ++c) {
        int d = c * 64 + lane;
        bool p = false;
        if (d < DIN) p = (__builtin_nontemporal_load(xrow + d) != 0.0f);
        unsigned long long m = __ballot(p ? 1 : 0);
        if (p) {
            int pos = cnt + __popcll(m & ((1ull << lane) - 1ull));
            lst[wv][pos] = d;
        }
        cnt += __popcll(m);
    }
    int cntp = (cnt + 7) & ~7;
    if (lane < cntp - cnt) lst[wv][cnt + lane] = DIN;   // zero row pad
    __syncthreads();

    const int lo = lane * 4;
    int i0 = 0, i1 = 0, i2 = 0, i3 = 0;     // accumulators, group A
    int j0 = 0, j1 = 0, j2 = 0, j3 = 0;     // accumulators, group B
    for (int k = 0; k < cntp; k += 8) {
        int4 ja = *(const int4*)&lst[wv][k];
        int4 jb = *(const int4*)&lst[wv][k + 4];
        s16x4 w0 = *(const s16x4*)(sT1 + ((size_t)ja.x << 8) + lo);
        s16x4 w1 = *(const s16x4*)(sT1 + ((size_t)ja.y << 8) + lo);
        s16x4 w2 = *(const s16x4*)(sT1 + ((size_t)ja.z << 8) + lo);
        s16x4 w3 = *(const s16x4*)(sT1 + ((size_t)ja.w << 8) + lo);
        s16x4 w4 = *(const s16x4*)(sT1 + ((size_t)jb.x << 8) + lo);
        s16x4 w5 = *(const s16x4*)(sT1 + ((size_t)jb.y << 8) + lo);
        s16x4 w6 = *(const s16x4*)(sT1 + ((size_t)jb.z << 8) + lo);
        s16x4 w7 = *(const s16x4*)(sT1 + ((size_t)jb.w << 8) + lo);
        i0 += (w0.x + w1.x) + (w2.x + w3.x);  j0 += (w4.x + w5.x) + (w6.x + w7.x);
        i1 += (w0.y + w1.y) + (w2.y + w3.y);  j1 += (w4.y + w5.y) + (w6.y + w7.y);
        i2 += (w0.z + w1.z) + (w2.z + w3.z);  j2 += (w4.z + w5.z) + (w6.z + w7.z);
        i3 += (w0.w + w1.w) + (w2.w + w3.w);  j3 += (w4.w + w5.w) + (w6.w + w7.w);
    }
    f32x4 acc = *(const f32x4*)(b_h1 + lo);
    acc.x += (float)(i0 + j0) * IQSCALE;
    acc.y += (float)(i1 + j1) * IQSCALE;
    acc.z += (float)(i2 + j2) * IQSCALE;
    acc.w += (float)(i3 + j3) * IQSCALE;
    __builtin_nontemporal_store(acc, (f32x4*)(Xp + ((size_t)t * BB + b) * H1 + lo));
}

// 16 gathered int16 adds from rows L[k..k+16) of a 256-stride table, col h.
// global_load_sshort sign-extends in HW: 1 load + 1 v_add_i32 per element.
__device__ __forceinline__ int gath16i(const short* __restrict__ W,
                                       const int* __restrict__ L, int k, int h) {
    int4 a = *(const int4*)(L + k);
    int4 b = *(const int4*)(L + k + 4);
    int4 c = *(const int4*)(L + k + 8);
    int4 d = *(const int4*)(L + k + 12);
    int v0  = W[(a.x << 8) + h], v1  = W[(a.y << 8) + h];
    int v2  = W[(a.z << 8) + h], v3  = W[(a.w << 8) + h];
    int v4  = W[(b.x << 8) + h], v5  = W[(b.y << 8) + h];
    int v6  = W[(b.z << 8) + h], v7  = W[(b.w << 8) + h];
    int v8  = W[(c.x << 8) + h], v9  = W[(c.y << 8) + h];
    int v10 = W[(c.z << 8) + h], v11 = W[(c.w << 8) + h];
    int v12 = W[(d.x << 8) + h], v13 = W[(d.y << 8) + h];
    int v14 = W[(d.z << 8) + h], v15 = W[(d.w << 8) + h];
    return (((v0 + v1) + (v2 + v3)) + ((v4 + v5) + (v6 + v7)))
         + (((v8 + v9) + (v10 + v11)) + ((v12 + v13) + (v14 + v15)));
}

// 16 fp32 output-weight values, stride-20 table.
__device__ __forceinline__ float gather16o(const float* __restrict__ W,
                                           const int* __restrict__ L, int k, int h) {
    int4 a = *(const int4*)(L + k);
    int4 b = *(const int4*)(L + k + 4);
    int4 c = *(const int4*)(L + k + 8);
    int4 d = *(const int4*)(L + k + 12);
    float v0  = W[a.x * DOUT + h], v1  = W[a.y * DOUT + h];
    float v2  = W[a.z * DOUT + h], v3  = W[a.w * DOUT + h];
    float v4  = W[b.x * DOUT + h], v5  = W[b.y * DOUT + h];
    float v6  = W[b.z * DOUT + h], v7  = W[b.w * DOUT + h];
    float v8  = W[c.x * DOUT + h], v9  = W[c.y * DOUT + h];
    float v10 = W[c.z * DOUT + h], v11 = W[c.w * DOUT + h];
    float v12 = W[d.x * DOUT + h], v13 = W[d.y * DOUT + h];
    float v14 = W[d.z * DOUT + h], v15 = W[d.w * DOUT + h];
    return (((v0 + v1) + (v2 + v3)) + ((v4 + v5) + (v6 + v7)))
         + (((v8 + v9) + (v10 + v11)) + ((v12 + v13) + (v14 + v15)));
}

// ---------------------------------------------------------------------------
// Recurrent loop: EXACT R4 structure (best measured), int16 gather tables.
// One 256-thread block per batch element, thread h = neuron h; flat spike
// lists padded to multiples of 16 (zero-row dummy); 4 barriers per timestep.
// ---------------------------------------------------------------------------
__global__ __launch_bounds__(256) void rec_k(
    const float* __restrict__ Xp,
    const short* __restrict__ sT11, const short* __restrict__ sT12,
    const short* __restrict__ sT22, const float* __restrict__ wT2o,
    const float* __restrict__ b_h2, const float* __restrict__ b_o,
    const float* __restrict__ tau_adp_h1, const float* __restrict__ tau_adp_h2,
    const float* __restrict__ tau_m_h1, const float* __restrict__ tau_m_h2,
    const float* __restrict__ tau_m_o,
    float* __restrict__ out) {
    const int h    = threadIdx.x;
    const int lane = h & 63;
    const int wv   = h >> 6;
    const int b    = blockIdx.x;

    __shared__ __align__(16) int lst1[272];
    __shared__ __align__(16) int lst2[272];
    __shared__ unsigned long long wmask[4];
    __shared__ float smo[DOUT];

    const float alpha1 = expf(-1.0f / tau_m_h1[h]);
    const float ro1    = expf(-1.0f / tau_adp_h1[h]);
    const float alpha2 = expf(-1.0f / tau_m_h2[h]);
    const float ro2    = expf(-1.0f / tau_adp_h2[h]);
    const float bh2v   = b_h2[h];
    float alpo = 0.f, bov = 0.f;
    if (h < DOUT) { alpo = expf(-1.0f / tau_m_o[h]); bov = b_o[h]; }

    float mem1 = 0.f, spk1 = 0.f, bb1v = BJ0;
    float mem2 = 0.f, spk2 = 0.f, bb2v = BJ0;
    float memo = 0.f, accs = 0.f;
    int n1p = 0, n2p = 0;

    float xp_cur = __builtin_nontemporal_load(Xp + ((size_t)b) * H1 + h);  // t=0

    for (int t = 0; t < TT; ++t) {
        float xp_nxt = 0.f;
        if (t + 1 < TT)
            xp_nxt = __builtin_nontemporal_load(Xp + ((size_t)(t + 1) * BB + b) * H1 + h);

        // ---- P1: fused gather over prev lists (sT11 | sT22 | wT2o) ----
        int ir1 = 0, ir2 = 0;
        float ro = 0.f;
        const bool doo = (h < DOUT) && (t > 0);
        const int kmax = n1p > n2p ? n1p : n2p;
        for (int k = 0; k < kmax; k += 16) {
            int s1 = 0, s2 = 0;
            float s3 = 0.f;
            if (k < n1p) s1 = gath16i(sT11, lst1, k, h);
            if (k < n2p) {
                s2 = gath16i(sT22, lst2, k, h);
                if (doo) s3 = gather16o(wT2o, lst2, k, h);
            }
            ir1 += s1; ir2 += s2; ro += s3;
        }

        // ---- U1: layer-1 update; output memo for step t-1 ----
        float r1 = (float)ir1 * IQSCALE;
        bb1v = ro1 * bb1v + BETAC * (1.f - ro1) * spk1;
        mem1 = mem1 * alpha1 - bb1v * spk1 + (1.f - alpha1) * (xp_cur + r1);
        float ns1 = (mem1 - bb1v - BJ0) > 0.f ? 1.f : 0.f;
        spk1 = ns1;
        unsigned long long m1 = __ballot(ns1 != 0.f ? 1 : 0);
        if (lane == 0) wmask[wv] = m1;
        if (doo) {
            memo = memo * alpo + (1.f - alpo) * (bov + ro);
            smo[h] = memo;
        }
        __syncthreads();                               // B1

        // ---- P2b: rebuild flat lst1 (+pad to 16-mult); softmax for t-1 ----
        {
            int pos = __popcll(m1 & ((1ull << lane) - 1ull));
            int tot = 0;
            for (int w = 0; w < 4; ++w) {
                unsigned long long mw = wmask[w];
                if (w < wv) pos += __popcll(mw);
                tot += __popcll(mw);
            }
            if (ns1 != 0.f) lst1[pos] = h;
            int np = (tot + 15) & ~15;
            if (h < np - tot) lst1[tot + h] = DUMMY;
            n1p = np;
        }
        if (doo) {
            float mx = smo[0];
            for (int i = 1; i < DOUT; ++i) mx = fmaxf(mx, smo[i]);
            float s = 0.f;
            for (int i = 0; i < DOUT; ++i) s += expf(smo[i] - mx);
            accs += expf(memo - mx) / s;
        }
        __syncthreads();                               // B2

        // ---- P3: gather sT12 over fresh lst1 ----
        int ir3 = 0;
        for (int k = 0; k < n1p; k += 16) ir3 += gath16i(sT12, lst1, k, h);

        // ---- U2: layer-2 update ----
        float r23 = (float)(ir2 + ir3) * IQSCALE;
        bb2v = ro2 * bb2v + BETAC * (1.f - ro2) * spk2;
        mem2 = mem2 * alpha2 - bb2v * spk2 + (1.f - alpha2) * (bh2v + r23);
        float ns2 = (mem2 - bb2v - BJ0) > 0.f ? 1.f : 0.f;
        spk2 = ns2;
        unsigned long long m2 = __ballot(ns2 != 0.f ? 1 : 0);
        if (lane == 0) wmask[wv] = m2;
        __syncthreads();                               // B3

        // ---- P4b: rebuild flat lst2 (+pad) ----
        {
            int pos = __popcll(m2 & ((1ull << lane) - 1ull));
            int tot = 0;
            for (int w = 0; w < 4; ++w) {
                unsigned long long mw = wmask[w];
                if (w < wv) pos += __popcll(mw);
                tot += __popcll(mw);
            }
            if (ns2 != 0.f) lst2[pos] = h;
            int np = (tot + 15) & ~15;
            if (h < np - tot) lst2[tot + h] = DUMMY;
            n2p = np;
        }
        __syncthreads();                               // B4

        xp_cur = xp_nxt;
    }

    // ---- Epilogue: output + softmax for the final timestep ----
    if (h < DOUT) {
        float ro = 0.f;
        for (int k = 0; k < n2p; k += 16) ro += gather16o(wT2o, lst2, k, h);
        memo = memo * alpo + (1.f - alpo) * (bov + ro);
        smo[h] = memo;
    }
    __syncthreads();
    if (h < DOUT) {
        float mx = smo[0];
        for (int i = 1; i < DOUT; ++i) mx = fmaxf(mx, smo[i]);
        float s = 0.f;
        for (int i = 0; i < DOUT; ++i) s += expf(smo[i] - mx);
        accs += expf(memo - mx) / s;
        out[b * DOUT + h] = accs;
    }
}

extern "C" void kernel_launch(void* const* d_in, const int* in_sizes, int n_in,
                              void* d_out, int out_size, void* d_ws, size_t ws_size,
                              hipStream_t stream) {
    const float* x          = (const float*)d_in[0];
    const float* w_i2h1     = (const float*)d_in[1];
    const float* w_h12h1    = (const float*)d_in[2];
    const float* w_h12h2    = (const float*)d_in[3];
    const float* w_h22h2    = (const float*)d_in[4];
    const float* w_h2o      = (const float*)d_in[5];
    const float* b_h1       = (const float*)d_in[6];
    const float* b_h2       = (const float*)d_in[7];
    const float* b_o        = (const float*)d_in[8];
    const float* tau_adp_h1 = (const float*)d_in[9];
    const float* tau_adp_h2 = (const float*)d_in[10];
    const float* tau_m_h1   = (const float*)d_in[11];
    const float* tau_m_h2   = (const float*)d_in[12];
    const float* tau_m_o    = (const float*)d_in[13];

    short* sws = (short*)d_ws;
    float* fws = (float*)d_ws;
    const short* sT1  = sws;
    const short* sT11 = sws + SOFF_T11;
    const short* sT12 = sws + SOFF_T12;
    const short* sT22 = sws + SOFF_T22;
    float* wT2o = fws + FOFF_W2O;
    float* Xp   = fws + FOFF_XP;

    transpose_all_k<<<(N_TRANS + 255) / 256, 256, 0, stream>>>(
        w_i2h1, w_h12h1, w_h12h2, w_h22h2, w_h2o, sws, fws);

    xproj_k<<<(TT * BB) / 4, 256, 0, stream>>>(x, sT1, b_h1, Xp);

    rec_k<<<BB, 256, 0, stream>>>(Xp, sT11, sT12, sT22, wT2o,
                                  b_h2, b_o, tau_adp_h1, tau_adp_h2,
                                  tau_m_h1, tau_m_h2, tau_m_o,
                                  (float*)d_out);
}